// Round 3
// baseline (374.309 us; speedup 1.0000x reference)
//
#include <hip/hip_runtime.h>
#include <stdint.h>
#include <math.h>

#define HW_ 16384   // H*W = 128*128
#define C_  256

typedef short bf16x8 __attribute__((ext_vector_type(8)));
typedef float f32x4  __attribute__((ext_vector_type(4)));
typedef unsigned int u32;

__device__ __forceinline__ short f2bf(float f) {
  union { float f; unsigned u; } v; v.f = f;
  unsigned u = v.u;
  u += 0x7fffu + ((u >> 16) & 1u);   // RNE
  return (short)(u >> 16);
}

// -------- kernel 0: prep (W -> bf16 in MFMA-fragment order, BN consts) ------
// Wp layout: idx = ks*8192 + kg*2048 + mf*128 + r*8 + e
//   lane (r = lane&15, kg = lane>>4) A-frag for (ks, mf) is 16 contiguous B.
__global__ __launch_bounds__(256) void k0_prep(
    const float* __restrict__ w_fe, const float* __restrict__ gamma,
    const float* __restrict__ beta, const float* __restrict__ mean,
    const float* __restrict__ var, unsigned short* __restrict__ Wp,
    float* __restrict__ scale, float* __restrict__ shift,
    float* __restrict__ pool_sum)
{
  int i = blockIdx.x * 256 + threadIdx.x;
  if (i < 131072) {
    int e  = i & 7;
    int r  = (i >> 3) & 15;
    int mf = (i >> 7) & 15;
    int kg = (i >> 11) & 3;
    int ks = i >> 13;
    int row = mf * 16 + r;              // output channel
    int k   = ks * 32 + kg * 8 + e;     // input channel (0..511)
    Wp[i] = (unsigned short)f2bf(w_fe[row * 512 + k]);
  }
  if (i < 2048) pool_sum[i] = 0.0f;     // kernel-ordered zeroing (no memset node)
  if (i < 256) {
    float sc = gamma[i] * rsqrtf(var[i] + 1e-5f);
    scale[i] = sc;
    shift[i] = beta[i] - mean[i] * sc;
  }
}

// ------- kernel 1: bf16 MFMA GEMM (W x cat) + BN + ReLU + pool partial ------
// No LDS staging, no main-loop barriers. A-frags straight from L1/L2-resident
// Wp; B-frags gathered coalesced from global. Block: 4 waves, BN=64 (16
// cols/wave), BM=256 (16 m-frags), BK=32. Grid: 8 * 256 = 2048 blocks.
__global__ __launch_bounds__(256) void k1_gemm_pool(
    const float* __restrict__ x1, const float* __restrict__ x2,
    const unsigned short* __restrict__ Wp,
    const float* __restrict__ scale, const float* __restrict__ shift,
    float* __restrict__ pool_sum, float* __restrict__ pool_part, int use_part)
{
  __shared__ float pool_l[256];

  const int tid  = threadIdx.x;
  const int lane = tid & 63;
  const int wave = tid >> 6;
  const int blk  = blockIdx.x;
  const int b    = blk >> 8;
  const int p0   = (blk & 255) * 64;

  const int r15 = lane & 15;
  const int kg  = lane >> 4;

  const float* xb1 = x1 + (size_t)b * C_ * HW_;
  const float* xb2 = x2 + (size_t)b * C_ * HW_;
  const int pcol = p0 + wave * 16 + r15;

  pool_l[tid] = 0.0f;

  f32x4 acc[16];
#pragma unroll
  for (int i = 0; i < 16; ++i) acc[i] = (f32x4){0.f, 0.f, 0.f, 0.f};

#pragma unroll 2
  for (int ks = 0; ks < 16; ++ks) {
    // ---- B-frag: 8 k-contiguous values, coalesced 256B/instr across lanes --
    const float* src = ((ks < 8) ? (xb1 + (size_t)(ks * 32 + kg * 8) * HW_)
                                 : (xb2 + (size_t)((ks - 8) * 32 + kg * 8) * HW_))
                       + pcol;
    float g0 = src[0 * HW_], g1 = src[1 * HW_], g2 = src[2 * HW_], g3 = src[3 * HW_];
    float g4 = src[4 * HW_], g5 = src[5 * HW_], g6 = src[6 * HW_], g7 = src[7 * HW_];

    // ---- A-frags: one dwordx4 each from fragment-ordered Wp (L1/L2 hot) ----
    const bf16x8* wrow =
        (const bf16x8*)(Wp + ((size_t)(ks * 4 + kg) * 256 + r15) * 8);

    bf16x8 bfr;
    bfr[0] = f2bf(g0); bfr[1] = f2bf(g1); bfr[2] = f2bf(g2); bfr[3] = f2bf(g3);
    bfr[4] = f2bf(g4); bfr[5] = f2bf(g5); bfr[6] = f2bf(g6); bfr[7] = f2bf(g7);

#pragma unroll
    for (int mf = 0; mf < 16; ++mf) {
      const bf16x8 af = wrow[mf * 16];   // +mf*256B
      acc[mf] = __builtin_amdgcn_mfma_f32_16x16x32_bf16(af, bfr, acc[mf], 0, 0, 0);
    }
  }

  __syncthreads();   // pool_l zeros visible to all

  // ---- epilogue: BN + ReLU, sum this wave's 16 positions, pool-reduce ----
  const int g4i = kg * 4;
#pragma unroll
  for (int mf = 0; mf < 16; ++mf) {
#pragma unroll
    for (int r = 0; r < 4; ++r) {
      int c = mf * 16 + g4i + r;                 // channel (C/D row)
      float s = acc[mf][r] * scale[c] + shift[c];
      s = fmaxf(s, 0.0f);
      s += __shfl_xor(s, 1);
      s += __shfl_xor(s, 2);
      s += __shfl_xor(s, 4);
      s += __shfl_xor(s, 8);                     // sum over the 16 cols
      if (r15 == 0) atomicAdd(&pool_l[c], s);    // 4 adds per channel (LDS)
    }
  }
  __syncthreads();
  if (use_part) {
    // idempotent plain store: immune to initial ws poison & replay ordering
    pool_part[(size_t)blk * 256 + tid] = pool_l[tid];
  } else {
    atomicAdd(&pool_sum[b * C_ + tid], pool_l[tid]);
  }
}

// -------- kernel 2: tiny MLPs -> per-(b,c) 3x3 kernels + attn coefs --------
__global__ __launch_bounds__(256) void k2_small(
    const float* __restrict__ pool_sum, const float* __restrict__ pool_part,
    int use_part,
    const float* __restrict__ w_cg1, const float* __restrict__ w_cg2,
    const float* __restrict__ w_ag1, const float* __restrict__ w_ag2,
    float* __restrict__ cw, float* __restrict__ coef)
{
  __shared__ float pl[256];
  __shared__ float hl[64];
  __shared__ float al[64];
  const int b = blockIdx.x, t = threadIdx.x;
  float v;
  if (use_part) {
    float s = 0.f;
    const float* base = pool_part + (size_t)b * 256 * 256 + t;
    for (int tile = 0; tile < 256; ++tile) s += base[tile * 256];  // fixed order
    v = s;
  } else {
    v = pool_sum[b * 256 + t];
  }
  pl[t] = v * (1.0f / 16384.0f);
  __syncthreads();
  if (t < 64) {
    float h = 0.f, a = 0.f;
    for (int i = 0; i < 256; ++i) {
      float p = pl[i];
      h += p * w_cg1[t * 256 + i];
      a += p * w_ag1[t * 256 + i];
    }
    hl[t] = fmaxf(h, 0.f);
    al[t] = fmaxf(a, 0.f);
  }
  __syncthreads();
#pragma unroll
  for (int e = 0; e < 9; ++e) {
    int o = e * 256 + t;                 // o in [0,2304) = c*9 + tap
    float s = 0.f;
    for (int j = 0; j < 64; ++j) s += hl[j] * w_cg2[o * 64 + j];
    cw[b * 2304 + o] = s;
  }
  if (t < 2) {
    float s = 0.f;
    for (int j = 0; j < 64; ++j) s += al[j] * w_ag2[t * 64 + j];
    coef[b * 2 + t] = 0.25f / (1.0f + expf(-s));   // 0.25 = LAMBDA_S * LAMBDA_C
  }
}

// -------- kernel 3: depthwise 3x3 (same kernel on x1 & x2) + combine --------
// Block: one 32-row strip of one (b,c) plane. Grid: 8*256*4 = 8192.
__global__ __launch_bounds__(256) void k3_dynconv(
    const float* __restrict__ x1, const float* __restrict__ x2,
    const float* __restrict__ cw, const float* __restrict__ coef,
    float* __restrict__ out)
{
  __shared__ float t1[34 * 128];
  __shared__ float t2[34 * 128];
  const int tid   = threadIdx.x;
  const int blk   = blockIdx.x;
  const int strip = blk & 3;
  const int c     = (blk >> 2) & 255;
  const int b     = blk >> 10;
  const int h0    = strip * 32;

  const size_t plane = ((size_t)b * C_ + c) * HW_;
  const float* p1 = x1 + plane;
  const float* p2 = x2 + plane;

  float tp[9];
#pragma unroll
  for (int e = 0; e < 9; ++e) tp[e] = cw[(b * C_ + c) * 9 + e];
  const float c1 = coef[b * 2 + 0];
  const float c2 = coef[b * 2 + 1];

  // rows h0-1 .. h0+32 (zero-pad outside), 34 rows x 128 cols, float4 loads
  for (int f = tid; f < 1088; f += 256) {
    int row = f >> 5;
    int c4  = (f & 31) << 2;
    int gh  = h0 - 1 + row;
    float4 v1 = make_float4(0.f, 0.f, 0.f, 0.f), v2 = v1;
    if (gh >= 0 && gh < 128) {
      v1 = *(const float4*)&p1[gh * 128 + c4];
      v2 = *(const float4*)&p2[gh * 128 + c4];
    }
    *(float4*)&t1[row * 128 + c4] = v1;
    *(float4*)&t2[row * 128 + c4] = v2;
  }
  __syncthreads();

  for (int i = 0; i < 16; ++i) {
    int q   = tid + i * 256;
    int r   = q >> 7;
    int col = q & 127;
    int lr  = r + 1;
    const bool lok = col > 0, rok = col < 127;
    float d1 = 0.f, d2 = 0.f;
#pragma unroll
    for (int dy = 0; dy < 3; ++dy) {
      const float* row1 = &t1[(lr - 1 + dy) * 128];
      const float* row2 = &t2[(lr - 1 + dy) * 128];
      float a1v = lok ? row1[col - 1] : 0.f;
      float b1v = row1[col];
      float e1v = rok ? row1[col + 1] : 0.f;
      float a2v = lok ? row2[col - 1] : 0.f;
      float b2v = row2[col];
      float e2v = rok ? row2[col + 1] : 0.f;
      d1 += a1v * tp[dy * 3 + 0] + b1v * tp[dy * 3 + 1] + e1v * tp[dy * 3 + 2];
      d2 += a2v * tp[dy * 3 + 0] + b2v * tp[dy * 3 + 1] + e2v * tp[dy * 3 + 2];
    }
    float v1 = t1[lr * 128 + col];
    float v2 = t2[lr * 128 + col];
    out[plane + (size_t)(h0 + r) * 128 + col] = 0.5f * (v1 + v2) + c1 * d1 + c2 * d2;
  }
}

extern "C" void kernel_launch(void* const* d_in, const int* in_sizes, int n_in,
                              void* d_out, int out_size, void* d_ws, size_t ws_size,
                              hipStream_t stream) {
  const float* x1    = (const float*)d_in[0];
  const float* x2    = (const float*)d_in[1];
  const float* w_fe  = (const float*)d_in[2];
  const float* gamma = (const float*)d_in[3];
  const float* beta  = (const float*)d_in[4];
  const float* mean  = (const float*)d_in[5];
  const float* var   = (const float*)d_in[6];
  const float* w_cg1 = (const float*)d_in[7];
  const float* w_cg2 = (const float*)d_in[8];
  const float* w_ag1 = (const float*)d_in[9];
  const float* w_ag2 = (const float*)d_in[10];
  float* out = (float*)d_out;

  // workspace layout
  char* ws = (char*)d_ws;
  unsigned short* Wp = (unsigned short*)(ws);              // [0, 262144)
  float* scale    = (float*)(ws + 262144);                 // 1 KB
  float* shift    = (float*)(ws + 263168);                 // 1 KB
  float* pool_sum = (float*)(ws + 264192);                 // 8 KB (fallback path)
  // big layout: per-block pool partials (2048 blocks x 256 ch = 2 MB)
  const size_t PART_OFF = 272384;
  const size_t BIG_CW   = PART_OFF + 2048ull * 256 * 4;    // 2369536
  const size_t BIG_COEF = BIG_CW + 73728;                  // 2443264
  const size_t BIG_END  = BIG_COEF + 64;                   // 2443328
  int use_part = (ws_size >= BIG_END) ? 1 : 0;
  float* pool_part = use_part ? (float*)(ws + PART_OFF) : pool_sum;
  float* cw   = (float*)(ws + (use_part ? BIG_CW   : 272384));
  float* coef = (float*)(ws + (use_part ? BIG_COEF : 346112));

  k0_prep<<<512, 256, 0, stream>>>(w_fe, gamma, beta, mean, var, Wp, scale, shift,
                                   pool_sum);
  k1_gemm_pool<<<2048, 256, 0, stream>>>(x1, x2, Wp, scale, shift,
                                         pool_sum, pool_part, use_part);
  k2_small<<<8, 256, 0, stream>>>(pool_sum, pool_part, use_part,
                                  w_cg1, w_cg2, w_ag1, w_ag2, cw, coef);
  k3_dynconv<<<8192, 256, 0, stream>>>(x1, x2, cw, coef, out);
}